// Round 4
// baseline (50.817 us; speedup 1.0000x reference)
//
#include <hip/hip_runtime.h>

// tensors (1024, 256, 16) fp32, WINDOW=5, STRIDES=1 -> S=252 windows,
// F=16 -> 120 triu pairs. out[b][p][s] fp32, p = triu_indices(16,1) order.
#define NB 1024
#define NT 256
#define NF 16
#define NW 5
#define NS 252   // NT - NW + 1
#define NPAIR 120
#define EPS 1e-5f

__global__ __launch_bounds__(256) void ts_corr_kernel(const float* __restrict__ in,
                                                      float* __restrict__ out) {
    const int b = blockIdx.x;
    const int tid = threadIdx.x;
    const bool active = tid < NS;
    const int s = active ? tid : NS - 1;  // inactive lanes compute a dup, skip writes

    // Load the 5x16 window into registers (vectorized float4 loads).
    const float* row0 = in + ((size_t)b * NT + s) * NF;
    float x[NW][NF];
    #pragma unroll
    for (int w = 0; w < NW; ++w) {
        const float4* r4 = reinterpret_cast<const float4*>(row0 + w * NF);
        #pragma unroll
        for (int q = 0; q < 4; ++q) {
            float4 v = r4[q];
            x[w][q * 4 + 0] = v.x;
            x[w][q * 4 + 1] = v.y;
            x[w][q * 4 + 2] = v.z;
            x[w][q * 4 + 3] = v.w;
        }
    }

    // Per-feature mean and 1/(std+eps), std with ddof=1 (divide by W-1=4).
    float mean[NF], rstd[NF];
    #pragma unroll
    for (int i = 0; i < NF; ++i) {
        float sum = 0.f, sq = 0.f;
        #pragma unroll
        for (int w = 0; w < NW; ++w) {
            sum += x[w][i];
            sq  += x[w][i] * x[w][i];
        }
        float m = sum * (1.0f / NW);
        mean[i] = m;
        float var = (sq - (float)NW * m * m) * (1.0f / (NW - 1));
        var = fmaxf(var, 0.0f);
        rstd[i] = 1.0f / (sqrtf(var) + EPS);
    }

    // 120 upper-triangle pairs; non-temporal scalar stores, coalesced per p.
    float* outb = out + (size_t)b * NPAIR * NS + s;
    int p = 0;
    #pragma unroll
    for (int i = 0; i < NF; ++i) {
        #pragma unroll
        for (int j = i + 1; j < NF; ++j) {
            float sxy = 0.f;
            #pragma unroll
            for (int w = 0; w < NW; ++w) sxy += x[w][i] * x[w][j];
            float cov = sxy * (1.0f / NW) - mean[i] * mean[j];
            float corr = cov * rstd[i] * rstd[j];
            if (active) __builtin_nontemporal_store(corr, &outb[(size_t)p * NS]);
            ++p;
        }
    }
}

extern "C" void kernel_launch(void* const* d_in, const int* in_sizes, int n_in,
                              void* d_out, int out_size, void* d_ws, size_t ws_size,
                              hipStream_t stream) {
    const float* in = (const float*)d_in[0];
    float* out = (float*)d_out;
    dim3 grid(NB);
    dim3 block(256);
    ts_corr_kernel<<<grid, block, 0, stream>>>(in, out);
}

// Round 5
// 34.999 us; speedup vs baseline: 1.4520x; 1.4520x over previous
//
#include <hip/hip_runtime.h>

// tensors (1024, 256, 16) fp32, WINDOW=5 -> S=252 windows, 120 triu pairs.
// out[b][p][s] fp32, p = np.triu_indices(16,1) order.
#define NB 1024
#define NT 256
#define NF 16
#define NW 5
#define NS 252
#define NPAIR 120
#define EPS 1e-5f

typedef float vf4 __attribute__((ext_vector_type(4)));

// triu_indices(16, k=1), row-major.
constexpr int IU[NPAIR] = {
  0,0,0,0,0,0,0,0,0,0,0,0,0,0,0,
  1,1,1,1,1,1,1,1,1,1,1,1,1,1,
  2,2,2,2,2,2,2,2,2,2,2,2,2,
  3,3,3,3,3,3,3,3,3,3,3,3,
  4,4,4,4,4,4,4,4,4,4,4,
  5,5,5,5,5,5,5,5,5,5,
  6,6,6,6,6,6,6,6,6,
  7,7,7,7,7,7,7,7,
  8,8,8,8,8,8,8,
  9,9,9,9,9,9,
  10,10,10,10,10,
  11,11,11,11,
  12,12,12,
  13,13,
  14};
constexpr int JU[NPAIR] = {
  1,2,3,4,5,6,7,8,9,10,11,12,13,14,15,
  2,3,4,5,6,7,8,9,10,11,12,13,14,15,
  3,4,5,6,7,8,9,10,11,12,13,14,15,
  4,5,6,7,8,9,10,11,12,13,14,15,
  5,6,7,8,9,10,11,12,13,14,15,
  6,7,8,9,10,11,12,13,14,15,
  7,8,9,10,11,12,13,14,15,
  8,9,10,11,12,13,14,15,
  9,10,11,12,13,14,15,
  10,11,12,13,14,15,
  11,12,13,14,15,
  12,13,14,15,
  13,14,15,
  14,15,
  15};

// One wave handles 30 pairs for its lane's 4 windows; one dwordx4 store/pair.
template<int G>
__device__ __forceinline__ void do_pairs(const float (*ldsT)[NT], int s0,
                                         const vf4* A, const vf4* Bm,
                                         float* outb, bool active) {
    float vi[8];
    #pragma unroll
    for (int k = 0; k < 30; ++k) {
        const int p = G * 30 + k;         // compile-time after unroll
        const int i = IU[p], j = JU[p];   // folds to constants
        if (k == 0 || IU[p] != IU[p - 1]) {     // compile-time condition
            const vf4* pi = reinterpret_cast<const vf4*>(&ldsT[i][s0]);
            vf4 a = pi[0], b = pi[1];
            vi[0]=a.x; vi[1]=a.y; vi[2]=a.z; vi[3]=a.w;
            vi[4]=b.x; vi[5]=b.y; vi[6]=b.z; vi[7]=b.w;
        }
        const vf4* pj = reinterpret_cast<const vf4*>(&ldsT[j][s0]);
        vf4 a = pj[0], b = pj[1];
        float z0 = vi[0]*a.x, z1 = vi[1]*a.y, z2 = vi[2]*a.z, z3 = vi[3]*a.w;
        float z4 = vi[4]*b.x, z5 = vi[5]*b.y, z6 = vi[6]*b.z, z7 = vi[7]*b.w;
        float t0 = z0+z1+z2+z3+z4;
        float t1 = t0 - z0 + z5;
        float t2 = t1 - z1 + z6;
        float t3 = t2 - z2 + z7;
        vf4 sxy = {t0, t1, t2, t3};
        vf4 corr = sxy * 0.2f * (A[i] * A[j]) - Bm[i] * Bm[j];
        if (active) *reinterpret_cast<vf4*>(outb + p * NS) = corr;
    }
}

__global__ __launch_bounds__(256) void ts_corr_kernel(const float* __restrict__ in,
                                                      float* __restrict__ out) {
    __shared__ __align__(16) float ldsT[NF][NT];   // transposed [feature][t], 16 KB
    const int b = blockIdx.x;
    const int tid = threadIdx.x;

    // Stage one batch transposed into LDS. Thread t loads row t (16 floats)
    // and scatter-writes lds[f][t]; bank = t%32 -> conflict-free.
    {
        const vf4* row = reinterpret_cast<const vf4*>(in + ((size_t)b * NT + tid) * NF);
        vf4 r0 = row[0], r1 = row[1], r2 = row[2], r3 = row[3];
        ldsT[ 0][tid]=r0.x; ldsT[ 1][tid]=r0.y; ldsT[ 2][tid]=r0.z; ldsT[ 3][tid]=r0.w;
        ldsT[ 4][tid]=r1.x; ldsT[ 5][tid]=r1.y; ldsT[ 6][tid]=r1.z; ldsT[ 7][tid]=r1.w;
        ldsT[ 8][tid]=r2.x; ldsT[ 9][tid]=r2.y; ldsT[10][tid]=r2.z; ldsT[11][tid]=r2.w;
        ldsT[12][tid]=r3.x; ldsT[13][tid]=r3.y; ldsT[14][tid]=r3.z; ldsT[15][tid]=r3.w;
    }
    __syncthreads();

    const int wid = tid >> 6;         // wave id = pair group (uniform per wave)
    int sq = tid & 63;                // s-quad index, 63 active lanes
    const bool active = sq < 63;
    if (!active) sq = 62;             // clamp: dup work, masked store
    const int s0 = sq * 4;            // windows s0..s0+3 use rows s0..s0+7

    // Per-feature stats for the 4 windows: A = 1/(std+eps), Bm = mean*A.
    vf4 A[NF], Bm[NF];
    #pragma unroll
    for (int f = 0; f < NF; ++f) {
        const vf4* pf = reinterpret_cast<const vf4*>(&ldsT[f][s0]);
        vf4 a = pf[0], bb = pf[1];
        float v0=a.x, v1=a.y, v2=a.z, v3=a.w, v4=bb.x, v5=bb.y, v6=bb.z, v7=bb.w;
        float t0 = v0+v1+v2+v3+v4;
        float t1 = t0 - v0 + v5;
        float t2 = t1 - v1 + v6;
        float t3 = t2 - v2 + v7;
        float z0=v0*v0, z1=v1*v1, z2=v2*v2, z3=v3*v3;
        float z4=v4*v4, z5=v5*v5, z6=v6*v6, z7=v7*v7;
        float q0 = z0+z1+z2+z3+z4;
        float q1 = q0 - z0 + z5;
        float q2 = q1 - z1 + z6;
        float q3 = q2 - z2 + z7;
        vf4 mean = vf4{t0,t1,t2,t3} * 0.2f;
        vf4 qq   = {q0,q1,q2,q3};
        vf4 var  = (qq - 5.0f * mean * mean) * 0.25f;
        vf4 rstd;
        rstd.x = 1.0f / (sqrtf(fmaxf(var.x, 0.0f)) + EPS);
        rstd.y = 1.0f / (sqrtf(fmaxf(var.y, 0.0f)) + EPS);
        rstd.z = 1.0f / (sqrtf(fmaxf(var.z, 0.0f)) + EPS);
        rstd.w = 1.0f / (sqrtf(fmaxf(var.w, 0.0f)) + EPS);
        A[f]  = rstd;
        Bm[f] = mean * rstd;
    }

    float* outb = out + (size_t)b * (NPAIR * NS) + s0;

    if      (wid == 0) do_pairs<0>(ldsT, s0, A, Bm, outb, active);
    else if (wid == 1) do_pairs<1>(ldsT, s0, A, Bm, outb, active);
    else if (wid == 2) do_pairs<2>(ldsT, s0, A, Bm, outb, active);
    else               do_pairs<3>(ldsT, s0, A, Bm, outb, active);
}

extern "C" void kernel_launch(void* const* d_in, const int* in_sizes, int n_in,
                              void* d_out, int out_size, void* d_ws, size_t ws_size,
                              hipStream_t stream) {
    const float* in = (const float*)d_in[0];
    float* out = (float*)d_out;
    ts_corr_kernel<<<dim3(NB), dim3(256), 0, stream>>>(in, out);
}

// Round 6
// 33.721 us; speedup vs baseline: 1.5070x; 1.0379x over previous
//
#include <hip/hip_runtime.h>

// tensors (1024, 256, 16) fp32, WINDOW=5 -> S=252 windows, 120 triu pairs.
// out[b][p][s] fp32, p = np.triu_indices(16,1) order.
// Thread owns (b, s-pair): windows 2q and 2q+1, rows 2q..2q+5 in registers.
#define NB 1024
#define NT 256
#define NF 16
#define NS 252
#define NPAIR 120
#define EPS 1e-5f

typedef float vf2 __attribute__((ext_vector_type(2)));

__global__ __launch_bounds__(128, 2) void ts_corr_kernel(const float* __restrict__ in,
                                                         float* __restrict__ out) {
    const int b = blockIdx.x;
    const int tid = threadIdx.x;            // 0..127
    const bool active = tid < (NS / 2);     // 126 s-pairs
    const int q = active ? tid : (NS / 2) - 1;
    const int r0 = q * 2;                   // rows r0..r0+5, windows r0 and r0+1

    // Load 6 rows x 16 features into registers (24 float4 loads).
    const float* base = in + ((size_t)b * NT + r0) * NF;
    float x[6][NF];
    #pragma unroll
    for (int w = 0; w < 6; ++w) {
        const float4* r4 = reinterpret_cast<const float4*>(base + w * NF);
        #pragma unroll
        for (int c = 0; c < 4; ++c) {
            float4 v = r4[c];
            x[w][c * 4 + 0] = v.x;
            x[w][c * 4 + 1] = v.y;
            x[w][c * 4 + 2] = v.z;
            x[w][c * 4 + 3] = v.w;
        }
    }

    // Per-feature stats for the 2 windows: A = rstd, M = mean*rstd.
    float A0[NF], A1[NF], M0[NF], M1[NF];
    #pragma unroll
    for (int i = 0; i < NF; ++i) {
        float v0 = x[0][i], v1 = x[1][i], v2 = x[2][i],
              v3 = x[3][i], v4 = x[4][i], v5 = x[5][i];
        float s0 = v0 + v1 + v2 + v3 + v4;
        float s1 = s0 - v0 + v5;
        float q0 = v0*v0 + v1*v1 + v2*v2 + v3*v3 + v4*v4;
        float q1 = q0 - v0*v0 + v5*v5;
        float m0 = s0 * 0.2f, m1 = s1 * 0.2f;
        float var0 = (q0 - 5.0f * m0 * m0) * 0.25f;
        float var1 = (q1 - 5.0f * m1 * m1) * 0.25f;
        float rs0 = 1.0f / (sqrtf(fmaxf(var0, 0.0f)) + EPS);
        float rs1 = 1.0f / (sqrtf(fmaxf(var1, 0.0f)) + EPS);
        A0[i] = rs0; A1[i] = rs1;
        M0[i] = m0 * rs0; M1[i] = m1 * rs1;
    }

    // 120 pairs; one float2 (8B) store per pair -> 512B per wave-store.
    float* outb = out + (size_t)b * (NPAIR * NS) + r0;
    int p = 0;
    #pragma unroll
    for (int i = 0; i < NF; ++i) {
        #pragma unroll
        for (int j = i + 1; j < NF; ++j) {
            float z0 = x[0][i]*x[0][j], z1 = x[1][i]*x[1][j], z2 = x[2][i]*x[2][j],
                  z3 = x[3][i]*x[3][j], z4 = x[4][i]*x[4][j], z5 = x[5][i]*x[5][j];
            float t0 = z0 + z1 + z2 + z3 + z4;
            float t1 = t0 - z0 + z5;
            float c0 = t0 * 0.2f * (A0[i] * A0[j]) - M0[i] * M0[j];
            float c1 = t1 * 0.2f * (A1[i] * A1[j]) - M1[i] * M1[j];
            vf2 c = {c0, c1};
            if (active) *reinterpret_cast<vf2*>(outb + (size_t)p * NS) = c;
            ++p;
        }
    }
}

extern "C" void kernel_launch(void* const* d_in, const int* in_sizes, int n_in,
                              void* d_out, int out_size, void* d_ws, size_t ws_size,
                              hipStream_t stream) {
    const float* in = (const float*)d_in[0];
    float* out = (float*)d_out;
    ts_corr_kernel<<<dim3(NB), dim3(128), 0, stream>>>(in, out);
}